// Round 1
// baseline (1164.196 us; speedup 1.0000x reference)
//
#include <hip/hip_runtime.h>
#include <math.h>

// Problem constants
#define NBATCH 16
#define NMENT  128          // M
#define NM     2048         // B*M rows
#define LSEQ   32
#define SSEQ   512
#define DD     768
#define NHEAD  12
#define HDIM   64
#define DFF    3072
#define NLAYER 4
#define NENT   50000

typedef __bf16 bf16;
typedef __attribute__((__ext_vector_type__(4))) float f32x4;
typedef __attribute__((__ext_vector_type__(8))) bf16 bf16x8;
typedef __attribute__((__ext_vector_type__(4))) bf16 bf16x4;

// ---------------------------------------------------------------------------
// async global->LDS, 16B per lane (dest = wave-uniform base + lane*16)
// ---------------------------------------------------------------------------
__device__ __forceinline__ void gl2lds16(const bf16* g, bf16* l) {
  __builtin_amdgcn_global_load_lds(
      (const __attribute__((address_space(1))) void*)g,
      (__attribute__((address_space(3))) void*)l, 16, 0, 0);
}

// ---------------------------------------------------------------------------
// fp32 -> bf16 flat convert (n4 = n/4 float4 chunks)
// ---------------------------------------------------------------------------
__global__ __launch_bounds__(256) void conv_bf16(const float* __restrict__ s,
                                                 bf16* __restrict__ d, int n4) {
  const int i = blockIdx.x * 256 + threadIdx.x;
  if (i >= n4) return;
  const float4 v = ((const float4*)s)[i];
  bf16x4 o;
  o.x = (bf16)v.x; o.y = (bf16)v.y; o.z = (bf16)v.z; o.w = (bf16)v.w;
  ((bf16x4*)d)[i] = o;
}

// fp32 [srows][scols] -> bf16 [drows][dcols] zero-padded
__global__ __launch_bounds__(256) void conv_pad(const float* __restrict__ s,
                                                bf16* __restrict__ d,
                                                int srows, int scols, int dcols,
                                                int total) {
  const int i = blockIdx.x * 256 + threadIdx.x;
  if (i >= total) return;
  const int r = i / dcols, c = i - r * dcols;
  const float v = (r < srows && c < scols) ? s[(size_t)r * scols + c] : 0.f;
  d[i] = (bf16)v;
}

// sum 4 fp32 partials (stride n4 float4s) -> bf16
__global__ __launch_bounds__(256) void red4_bf16(const float* __restrict__ p,
                                                 bf16* __restrict__ d, int n4) {
  const int i = blockIdx.x * 256 + threadIdx.x;
  if (i >= n4) return;
  const float4 a = ((const float4*)p)[i];
  const float4 b = ((const float4*)p)[i + (size_t)n4];
  const float4 c = ((const float4*)p)[i + 2 * (size_t)n4];
  const float4 e = ((const float4*)p)[i + 3 * (size_t)n4];
  bf16x4 o;
  o.x = (bf16)(a.x + b.x + c.x + e.x);
  o.y = (bf16)(a.y + b.y + c.y + e.y);
  o.z = (bf16)(a.z + b.z + c.z + e.z);
  o.w = (bf16)(a.w + b.w + c.w + e.w);
  ((bf16x4*)d)[i] = o;
}

// ---------------------------------------------------------------------------
// t[b,l] = dot(lhs[b,l,:], attn_w)
// ---------------------------------------------------------------------------
__global__ __launch_bounds__(64) void tdot_kernel(const float* __restrict__ lhs,
                                                  const float* __restrict__ aw,
                                                  float* __restrict__ t) {
  const int bl = blockIdx.x;
  const int b = bl >> 5, l = bl & 31;
  const int lane = threadIdx.x;
  const float* row = lhs + ((size_t)b * SSEQ + l) * DD;
  float s = 0.f;
#pragma unroll
  for (int u = 0; u < DD / 64; ++u)
    s += row[lane + 64 * u] * aw[lane + 64 * u];
#pragma unroll
  for (int off = 32; off > 0; off >>= 1) s += __shfl_down(s, off);
  if (lane == 0) t[bl] = s;
}

// ---------------------------------------------------------------------------
// Mention pooling -> X (fp32) + Xb (bf16 shadow for MFMA GEMMs)
// ---------------------------------------------------------------------------
__global__ __launch_bounds__(256) void pool_kernel(const float* __restrict__ lhs,
                                                   const int* __restrict__ pos,
                                                   const int* __restrict__ msk,
                                                   const float* __restrict__ t,
                                                   float* __restrict__ X,
                                                   bf16* __restrict__ Xb) {
  __shared__ float wgt[LSEQ];
  __shared__ int ok[LSEQ];
  const int bm = blockIdx.x;
  const int b = bm >> 7;
  const int tid = threadIdx.x;
  if (tid < LSEQ) ok[tid] = (pos[(size_t)bm * LSEQ + tid] != -1) ? 1 : 0;
  __syncthreads();
  if (tid == 0) {
    const int mk = (msk[bm] != 0) ? 1 : 0;
    int run = 1;
    float lg[LSEQ];
    int vld[LSEQ];
#pragma unroll
    for (int l = 0; l < LSEQ; ++l) {
      run &= ok[l];
      vld[l] = mk & run;
      lg[l] = vld[l] ? t[b * LSEQ + l] : 0.f;
    }
    float mx = lg[0];
#pragma unroll
    for (int l = 1; l < LSEQ; ++l) mx = fmaxf(mx, lg[l]);
    float s = 0.f;
#pragma unroll
    for (int l = 0; l < LSEQ; ++l) { lg[l] = expf(lg[l] - mx); s += lg[l]; }
    const float inv = 1.f / s;
#pragma unroll
    for (int l = 0; l < LSEQ; ++l) wgt[l] = vld[l] ? lg[l] * inv : 0.f;
  }
  __syncthreads();
#pragma unroll
  for (int u = 0; u < 3; ++u) {
    const int d = tid + 256 * u;
    float acc = 0.f;
#pragma unroll
    for (int l = 0; l < LSEQ; ++l)
      acc += wgt[l] * lhs[((size_t)b * SSEQ + l) * DD + d];
    X[(size_t)bm * DD + d] = acc;
    Xb[(size_t)bm * DD + d] = (bf16)acc;
  }
}

// ---------------------------------------------------------------------------
// MFMA GEMM (m97 structure): C[M,N] = A[M,K](bf16) * B[N,K](bf16)^T + bias
// 128x128 tile, BK=32, 256 thr = 4 waves (2x2 of 64x64 wave tiles),
// global_load_lds width=16 staging, ds_read_b128 fragments,
// 16x mfma_f32_16x16x32_bf16 per wave per K-step.
// Split-K: blockIdx.z processes K window [z*K, (z+1)*K) of lda/ldb-strided
// operands and writes its partial to Cp + z*rows*ldc. Callers sum partials
// in the consumer (ln_kernel / red4_bf16). K multiple of 32; M,N mult of 128
// (only the store path is N-guarded via GUARD_N).
// ---------------------------------------------------------------------------
template <int OUT_BF16, int RELU, int HAS_BIAS, int GUARD_N>
__global__ __launch_bounds__(256) void gemm_mfma(const bf16* __restrict__ A,
                                                 const bf16* __restrict__ B,
                                                 const float* __restrict__ bias,
                                                 void* __restrict__ Cp,
                                                 int K, int lda, int ldb,
                                                 int ldc, int ncols) {
  __shared__ __align__(16) bf16 As[128 * 32];
  __shared__ __align__(16) bf16 Bs[128 * 32];
  const int tid = threadIdx.x;
  const int wave = tid >> 6, lane = tid & 63;
  const int rb = blockIdx.y * 128, cb = blockIdx.x * 128;
  const int wm = (wave >> 1) * 64, wn = (wave & 1) * 64;
  const int koff = blockIdx.z * K;

  // staging: wave w covers rows [w*32, w*32+32); lane -> (row, k) so that
  // LDS element index == wave*1024 + lane*8 (row-major [128][32], no pad)
  const int sr = wave * 32 + (lane >> 2);
  const int sk = (lane & 3) * 8;
  const bf16* ga0 = A + (size_t)(rb + sr) * lda + koff + sk;
  const bf16* ga1 = A + (size_t)(rb + sr + 16) * lda + koff + sk;
  const bf16* gb0 = B + (size_t)(cb + sr) * ldb + koff + sk;
  const bf16* gb1 = B + (size_t)(cb + sr + 16) * ldb + koff + sk;
  bf16* sa0 = As + wave * 1024;
  bf16* sa1 = As + wave * 1024 + 512;
  bf16* sb0 = Bs + wave * 1024;
  bf16* sb1 = Bs + wave * 1024 + 512;

  // fragment addressing: A[m=lane&15][k=(lane>>4)*8 + j]
  const int fr = lane & 15, fk = (lane >> 4) * 8;

  f32x4 acc[4][4];
#pragma unroll
  for (int i = 0; i < 4; ++i)
#pragma unroll
    for (int j = 0; j < 4; ++j) acc[i][j] = (f32x4)0.f;

  for (int kb = 0; kb < K; kb += 32) {
    gl2lds16(ga0, sa0); gl2lds16(ga1, sa1);
    gl2lds16(gb0, sb0); gl2lds16(gb1, sb1);
    ga0 += 32; ga1 += 32; gb0 += 32; gb1 += 32;
    __syncthreads();   // drains vmcnt (global_load_lds) before LDS reads
    bf16x8 af[4], bfr[4];
#pragma unroll
    for (int i = 0; i < 4; ++i)
      af[i] = *(const bf16x8*)(As + (wm + i * 16 + fr) * 32 + fk);
#pragma unroll
    for (int j = 0; j < 4; ++j)
      bfr[j] = *(const bf16x8*)(Bs + (wn + j * 16 + fr) * 32 + fk);
#pragma unroll
    for (int i = 0; i < 4; ++i)
#pragma unroll
      for (int j = 0; j < 4; ++j)
        acc[i][j] = __builtin_amdgcn_mfma_f32_16x16x32_bf16(af[i], bfr[j],
                                                            acc[i][j], 0, 0, 0);
    __syncthreads();   // protect LDS from next iteration's staging
  }

  // epilogue: C/D layout col=lane&15, row=(lane>>4)*4+reg (m89-verified)
  const size_t zoff = (size_t)blockIdx.z * (size_t)(gridDim.y << 7) * ldc;
  const int r0 = rb + wm + ((lane >> 4) << 2);
  const int c0 = cb + wn + fr;
#pragma unroll
  for (int i = 0; i < 4; ++i) {
#pragma unroll
    for (int j = 0; j < 4; ++j) {
      const int col = c0 + j * 16;
      if (GUARD_N && col >= ncols) continue;
      const float bv = HAS_BIAS ? bias[col] : 0.f;
#pragma unroll
      for (int r = 0; r < 4; ++r) {
        float v = acc[i][j][r] + bv;
        if (RELU) v = fmaxf(v, 0.f);
        const int row = r0 + i * 16 + r;
        if (OUT_BF16)
          ((bf16*)Cp)[zoff + (size_t)row * ldc + col] = (bf16)v;
        else
          ((float*)Cp)[zoff + (size_t)row * ldc + col] = v;
      }
    }
  }
}

// ---------------------------------------------------------------------------
// Attention: one block per (b, h). Reads fp32 QKV, writes bf16 AO.
// ---------------------------------------------------------------------------
__global__ __launch_bounds__(256) void attn_kernel(const float* __restrict__ qkv,
                                                   bf16* __restrict__ ao) {
  __shared__ float smem[2 * 64 * 132 + 128 * 132];
  float* Qs = smem;                  // [64][132] k-major
  float* Ks = smem + 64 * 132;       // [64][132]
  float* Ps = smem + 2 * 64 * 132;   // [128][132] c-major
  float* Vs = smem;                  // alias after S built: [128][68]

  const int tid = threadIdx.x;
  const int b = blockIdx.x / NHEAD;
  const int h = blockIdx.x % NHEAD;
  const float* base = qkv + (size_t)b * NMENT * (3 * DD) + h * HDIM;

#pragma unroll
  for (int it = 0; it < 8; ++it) {
    const int idx = tid + it * 256;
    const int m = idx >> 4;
    const int d0 = (idx & 15) * 4;
    const float4 q = *(const float4*)(base + (size_t)m * (3 * DD) + d0);
    const float4 k = *(const float4*)(base + (size_t)m * (3 * DD) + DD + d0);
    Qs[(d0 + 0) * 132 + m] = q.x; Qs[(d0 + 1) * 132 + m] = q.y;
    Qs[(d0 + 2) * 132 + m] = q.z; Qs[(d0 + 3) * 132 + m] = q.w;
    Ks[(d0 + 0) * 132 + m] = k.x; Ks[(d0 + 1) * 132 + m] = k.y;
    Ks[(d0 + 2) * 132 + m] = k.z; Ks[(d0 + 3) * 132 + m] = k.w;
  }
  __syncthreads();

  const int tm = (tid >> 4) * 8;
  const int tn = (tid & 15) * 8;
  {
    float acc[8][8];
#pragma unroll
    for (int i = 0; i < 8; ++i)
#pragma unroll
      for (int j = 0; j < 8; ++j) acc[i][j] = 0.f;
    for (int d = 0; d < HDIM; ++d) {
      float a[8], bv[8];
      *(float4*)&a[0] = *(const float4*)&Qs[d * 132 + tm];
      *(float4*)&a[4] = *(const float4*)&Qs[d * 132 + tm + 4];
      *(float4*)&bv[0] = *(const float4*)&Ks[d * 132 + tn];
      *(float4*)&bv[4] = *(const float4*)&Ks[d * 132 + tn + 4];
#pragma unroll
      for (int i = 0; i < 8; ++i)
#pragma unroll
        for (int j = 0; j < 8; ++j)
          acc[i][j] = fmaf(a[i], bv[j], acc[i][j]);
    }
    const float scale = 0.125f;
#pragma unroll
    for (int i = 0; i < 8; ++i)
#pragma unroll
      for (int j = 0; j < 8; ++j)
        Ps[(tn + j) * 132 + (tm + i)] = acc[i][j] * scale;
  }
  __syncthreads();

#pragma unroll
  for (int it = 0; it < 8; ++it) {
    const int idx = tid + it * 256;
    const int m = idx >> 4;
    const int d0 = (idx & 15) * 4;
    const float4 v = *(const float4*)(base + (size_t)m * (3 * DD) + 2 * DD + d0);
    *(float4*)&Vs[m * 68 + d0] = v;
  }
  if (tid < NMENT) {
    const int r = tid;
    float mx = -1e30f;
    for (int c = 0; c < NMENT; ++c) mx = fmaxf(mx, Ps[c * 132 + r]);
    float s = 0.f;
    for (int c = 0; c < NMENT; ++c) {
      const float e = expf(Ps[c * 132 + r] - mx);
      Ps[c * 132 + r] = e;
      s += e;
    }
    const float inv = 1.f / s;
    for (int c = 0; c < NMENT; ++c) Ps[c * 132 + r] *= inv;
  }
  __syncthreads();

  const int om = (tid >> 4) * 8;
  const int od = (tid & 15) * 4;
  float oacc[8][4];
#pragma unroll
  for (int i = 0; i < 8; ++i)
#pragma unroll
    for (int j = 0; j < 4; ++j) oacc[i][j] = 0.f;
  for (int c = 0; c < NMENT; ++c) {
    float p[8];
    *(float4*)&p[0] = *(const float4*)&Ps[c * 132 + om];
    *(float4*)&p[4] = *(const float4*)&Ps[c * 132 + om + 4];
    const float4 vv = *(const float4*)&Vs[c * 68 + od];
#pragma unroll
    for (int i = 0; i < 8; ++i) {
      oacc[i][0] = fmaf(p[i], vv.x, oacc[i][0]);
      oacc[i][1] = fmaf(p[i], vv.y, oacc[i][1]);
      oacc[i][2] = fmaf(p[i], vv.z, oacc[i][2]);
      oacc[i][3] = fmaf(p[i], vv.w, oacc[i][3]);
    }
  }
#pragma unroll
  for (int i = 0; i < 8; ++i) {
    bf16x4 ov;
    ov.x = (bf16)oacc[i][0]; ov.y = (bf16)oacc[i][1];
    ov.z = (bf16)oacc[i][2]; ov.w = (bf16)oacc[i][3];
    *(bf16x4*)(ao + (size_t)(b * NMENT + om + i) * DD + h * HDIM + od) = ov;
  }
}

// ---------------------------------------------------------------------------
// out = LayerNorm(x + bias + sum_{n<NS} y_n) * w + b -> fp32 o + bf16 ob
// y_n are split-K GEMM partials at stride NM*DD; bias is the GEMM bias
// folded here (split partials carry no bias).
// ---------------------------------------------------------------------------
template <int NS>
__global__ __launch_bounds__(256) void ln_kernel(const float* __restrict__ x,
                                                 const float* __restrict__ y,
                                                 const float* __restrict__ bias,
                                                 const float* __restrict__ w,
                                                 const float* __restrict__ bb,
                                                 float* __restrict__ o,
                                                 bf16* __restrict__ ob) {
  __shared__ float red1[4], red2[4];
  __shared__ float mshare, vshare;
  const int row = blockIdx.x;
  const int tid = threadIdx.x;
  const int wave = tid >> 6, lane = tid & 63;
  const float* xr = x + (size_t)row * DD;
  const float* yr = y + (size_t)row * DD;
  float v[3];
  float s = 0.f;
#pragma unroll
  for (int u = 0; u < 3; ++u) {
    const int d = tid + 256 * u;
    float acc = xr[d] + bias[d];
#pragma unroll
    for (int n = 0; n < NS; ++n) acc += yr[(size_t)n * NM * DD + d];
    v[u] = acc;
    s += acc;
  }
#pragma unroll
  for (int off = 32; off > 0; off >>= 1) s += __shfl_down(s, off);
  if (lane == 0) red1[wave] = s;
  __syncthreads();
  if (tid == 0) mshare = (red1[0] + red1[1] + red1[2] + red1[3]) * (1.f / DD);
  __syncthreads();
  const float mean = mshare;
  float q = 0.f;
#pragma unroll
  for (int u = 0; u < 3; ++u) { const float d = v[u] - mean; q += d * d; }
#pragma unroll
  for (int off = 32; off > 0; off >>= 1) q += __shfl_down(q, off);
  if (lane == 0) red2[wave] = q;
  __syncthreads();
  if (tid == 0)
    vshare = rsqrtf((red2[0] + red2[1] + red2[2] + red2[3]) * (1.f / DD) + 1e-5f);
  __syncthreads();
  const float rstd = vshare;
  float* orow = o + (size_t)row * DD;
  bf16* brow = ob + (size_t)row * DD;
#pragma unroll
  for (int u = 0; u < 3; ++u) {
    const int d = tid + 256 * u;
    const float r = (v[u] - mean) * rstd * w[d] + bb[d];
    orow[d] = r;
    brow[d] = (bf16)r;
  }
}

// ---------------------------------------------------------------------------
extern "C" void kernel_launch(void* const* d_in, const int* in_sizes, int n_in,
                              void* d_out, int out_size, void* d_ws, size_t ws_size,
                              hipStream_t stream) {
  const float* lhs    = (const float*)d_in[0];
  const int*   pos    = (const int*)d_in[1];
  const int*   msk    = (const int*)d_in[2];
  const float* attn_w = (const float*)d_in[3];
  // d_in[4] attn_b cancels in softmax
  const float* qkv_w  = (const float*)d_in[5];
  const float* qkv_b  = (const float*)d_in[6];
  const float* out_w  = (const float*)d_in[7];
  const float* out_b  = (const float*)d_in[8];
  const float* ff1_w  = (const float*)d_in[11];
  const float* ff1_b  = (const float*)d_in[12];
  const float* ff2_w  = (const float*)d_in[13];
  const float* ff2_b  = (const float*)d_in[14];
  const float* ln1_w  = (const float*)d_in[9];
  const float* ln1_b  = (const float*)d_in[10];
  const float* ln2_w  = (const float*)d_in[15];
  const float* ln2_b  = (const float*)d_in[16];
  const float* cls_w1 = (const float*)d_in[17];
  const float* cls_w2 = (const float*)d_in[18];
  const float* cls_b2 = (const float*)d_in[19];
  float* out = (float*)d_out;

  // workspace carve-up (~121 MB total).
  // SCR is a union region (25.2 MB = 4*NM*DD fp32):
  //   - holds QKV fp32 [NM][2304] between the QKV GEMM and attn
  //   - then holds split-K partials (<=4 x [NM][DD] fp32) for out-proj/FF2
  //   - holds 4 x [NM][128] partials for the Hb classifier stage
  char* p = (char*)d_ws;
  auto carve = [&](size_t bytes) {
    void* r = (void*)p;
    p += (bytes + 255) & ~(size_t)255;
    return r;
  };
  float* T    = (float*)carve(512 * 4);
  float* X    = (float*)carve((size_t)NM * DD * 4);
  float* SCR  = (float*)carve((size_t)4 * NM * DD * 4);
  bf16* Xb    = (bf16*)carve((size_t)NM * DD * 2);
  bf16* AOb   = (bf16*)carve((size_t)NM * DD * 2);
  bf16* H1    = (bf16*)carve((size_t)NM * DFF * 2);
  bf16* Hb    = (bf16*)carve((size_t)NM * 128 * 2);
  bf16* Wqkv  = (bf16*)carve((size_t)NLAYER * 3 * DD * DD * 2);
  bf16* Wout  = (bf16*)carve((size_t)NLAYER * DD * DD * 2);
  bf16* Wff1  = (bf16*)carve((size_t)NLAYER * DFF * DD * 2);
  bf16* Wff2  = (bf16*)carve((size_t)NLAYER * DD * DFF * 2);
  bf16* Wc1   = (bf16*)carve((size_t)128 * DD * 2);
  bf16* Wc2   = (bf16*)carve((size_t)50048 * 128 * 2);

  // weight conversions (every launch; ~210 MB traffic ~ 40 us)
  {
    const int n_qkv = NLAYER * 3 * DD * DD / 4;   // 1,769,472
    const int n_out = NLAYER * DD * DD / 4;       //   589,824
    const int n_ff  = NLAYER * DFF * DD / 4;      // 2,359,296
    conv_bf16<<<(n_qkv + 255) / 256, 256, 0, stream>>>(qkv_w, Wqkv, n_qkv);
    conv_bf16<<<(n_out + 255) / 256, 256, 0, stream>>>(out_w, Wout, n_out);
    conv_bf16<<<(n_ff + 255) / 256, 256, 0, stream>>>(ff1_w, Wff1, n_ff);
    conv_bf16<<<(n_ff + 255) / 256, 256, 0, stream>>>(ff2_w, Wff2, n_ff);
    const int t1 = 128 * DD;          // 98,304
    const int t2 = 50048 * 128;       // 6,406,144
    conv_pad<<<(t1 + 255) / 256, 256, 0, stream>>>(cls_w1, Wc1, 100, DD, DD, t1);
    conv_pad<<<(t2 + 255) / 256, 256, 0, stream>>>(cls_w2, Wc2, NENT, 100, 128, t2);
  }

  tdot_kernel<<<NBATCH * LSEQ, 64, 0, stream>>>(lhs, attn_w, T);
  pool_kernel<<<NM, 256, 0, stream>>>(lhs, pos, msk, T, X, Xb);

  for (int i = 0; i < NLAYER; ++i) {
    // QKV projection: [2048][768] x [2304][768]^T -> SCR fp32 [2048][2304]
    gemm_mfma<0, 0, 1, 0><<<dim3(18, 16), 256, 0, stream>>>(
        Xb, Wqkv + (size_t)i * 3 * DD * DD, qkv_b + (size_t)i * 3 * DD, SCR,
        DD, DD, DD, 3 * DD, 3 * DD);
    attn_kernel<<<NBATCH * NHEAD, 256, 0, stream>>>(SCR, AOb);
    // out-proj split-K x2 (96 -> 192 blocks): partials, bias folded into ln1
    gemm_mfma<0, 0, 0, 0><<<dim3(6, 16, 2), 256, 0, stream>>>(
        AOb, Wout + (size_t)i * DD * DD, nullptr, SCR,
        DD / 2, DD, DD, DD, DD);
    ln_kernel<2><<<NM, 256, 0, stream>>>(X, SCR, out_b + (size_t)i * DD,
                                         ln1_w + (size_t)i * DD,
                                         ln1_b + (size_t)i * DD, X, Xb);
    // FF1: full-K (384 blocks already fill the chip)
    gemm_mfma<1, 1, 1, 0><<<dim3(24, 16), 256, 0, stream>>>(
        Xb, Wff1 + (size_t)i * DFF * DD, ff1_b + (size_t)i * DFF, H1,
        DD, DD, DD, DFF, DFF);
    // FF2 split-K x4 (96 -> 384 blocks, K 3072 -> 768/split)
    gemm_mfma<0, 0, 0, 0><<<dim3(6, 16, 4), 256, 0, stream>>>(
        H1, Wff2 + (size_t)i * DD * DFF, nullptr, SCR,
        DFF / 4, DFF, DFF, DD, DD);
    ln_kernel<4><<<NM, 256, 0, stream>>>(X, SCR, ff2_b + (size_t)i * DD,
                                         ln2_w + (size_t)i * DD,
                                         ln2_b + (size_t)i * DD, X, Xb);
  }

  // classifier stage 1: Xb @ Wc1^T, split-K x4 (16 -> 64 blocks) -> fp32
  // partials in SCR, then reduce+convert -> Hb [2048][128] bf16
  gemm_mfma<0, 0, 0, 0><<<dim3(1, 16, 4), 256, 0, stream>>>(
      Xb, Wc1, nullptr, SCR, DD / 4, DD, DD, 128, 128);
  {
    const int n4 = NM * 128 / 4;  // 65,536 float4 chunks per partial
    red4_bf16<<<(n4 + 255) / 256, 256, 0, stream>>>(SCR, Hb, n4);
  }
  // classifier stage 2: Hb @ Wc2^T + b -> out [2048][50000] fp32
  gemm_mfma<0, 0, 1, 1><<<dim3(391, 16), 256, 0, stream>>>(
      Hb, Wc2, cls_b2, out, 128, 128, 128, NENT, NENT);
}

// Round 2
// 1120.509 us; speedup vs baseline: 1.0390x; 1.0390x over previous
//
#include <hip/hip_runtime.h>
#include <math.h>

// Problem constants
#define NBATCH 16
#define NMENT  128          // M
#define NM     2048         // B*M rows
#define LSEQ   32
#define SSEQ   512
#define DD     768
#define NHEAD  12
#define HDIM   64
#define DFF    3072
#define NLAYER 4
#define NENT   50000

typedef __bf16 bf16;
typedef __attribute__((__ext_vector_type__(4))) float f32x4;
typedef __attribute__((__ext_vector_type__(8))) bf16 bf16x8;
typedef __attribute__((__ext_vector_type__(4))) bf16 bf16x4;

// ---------------------------------------------------------------------------
// async global->LDS, 16B per lane (dest = wave-uniform base + lane*16)
// ---------------------------------------------------------------------------
__device__ __forceinline__ void gl2lds16(const bf16* g, bf16* l) {
  __builtin_amdgcn_global_load_lds(
      (const __attribute__((address_space(1))) void*)g,
      (__attribute__((address_space(3))) void*)l, 16, 0, 0);
}

// ---------------------------------------------------------------------------
// Fused weight conversion: all fp32->bf16 weight converts in ONE dispatch.
// Work items: float4 chunks for the flat converts, single elements for the
// zero-padded classifier weights.
// ---------------------------------------------------------------------------
#define C_QKV (NLAYER * 3 * DD * DD / 4)   // 1,769,472 float4 chunks
#define C_OUT (NLAYER * DD * DD / 4)       //   589,824
#define C_FF  (NLAYER * DFF * DD / 4)      // 2,359,296
#define C_W1  (128 * DD)                   //    98,304 elements
#define C_W2  (50048 * 128)                // 6,406,144 elements
#define C_TOTAL (C_QKV + C_OUT + 2 * C_FF + C_W1 + C_W2)

__device__ __forceinline__ void cvt4(const float* s, bf16* d, int i) {
  const float4 v = ((const float4*)s)[i];
  bf16x4 o;
  o.x = (bf16)v.x; o.y = (bf16)v.y; o.z = (bf16)v.z; o.w = (bf16)v.w;
  ((bf16x4*)d)[i] = o;
}

__global__ __launch_bounds__(256) void conv_all(
    const float* __restrict__ qkv_w, const float* __restrict__ out_w,
    const float* __restrict__ ff1_w, const float* __restrict__ ff2_w,
    const float* __restrict__ cls_w1, const float* __restrict__ cls_w2,
    bf16* __restrict__ Wqkv, bf16* __restrict__ Wout, bf16* __restrict__ Wff1,
    bf16* __restrict__ Wff2, bf16* __restrict__ Wc1, bf16* __restrict__ Wc2) {
  int i = blockIdx.x * 256 + threadIdx.x;
  if (i < C_QKV) { cvt4(qkv_w, Wqkv, i); return; }
  i -= C_QKV;
  if (i < C_OUT) { cvt4(out_w, Wout, i); return; }
  i -= C_OUT;
  if (i < C_FF) { cvt4(ff1_w, Wff1, i); return; }
  i -= C_FF;
  if (i < C_FF) { cvt4(ff2_w, Wff2, i); return; }
  i -= C_FF;
  if (i < C_W1) {  // [100][768] -> [128][768] zero-padded
    const int r = i / DD;
    Wc1[i] = (bf16)((r < 100) ? cls_w1[i] : 0.f);
    return;
  }
  i -= C_W1;
  if (i < C_W2) {  // [50000][100] -> [50048][128] zero-padded
    const int r = i >> 7, c = i & 127;
    const float v = (r < NENT && c < 100) ? cls_w2[r * 100 + c] : 0.f;
    Wc2[i] = (bf16)v;
  }
}

// sum 4 fp32 partials (stride n4 float4s) -> bf16
__global__ __launch_bounds__(256) void red4_bf16(const float* __restrict__ p,
                                                 bf16* __restrict__ d, int n4) {
  const int i = blockIdx.x * 256 + threadIdx.x;
  if (i >= n4) return;
  const float4 a = ((const float4*)p)[i];
  const float4 b = ((const float4*)p)[i + (size_t)n4];
  const float4 c = ((const float4*)p)[i + 2 * (size_t)n4];
  const float4 e = ((const float4*)p)[i + 3 * (size_t)n4];
  bf16x4 o;
  o.x = (bf16)(a.x + b.x + c.x + e.x);
  o.y = (bf16)(a.y + b.y + c.y + e.y);
  o.z = (bf16)(a.z + b.z + c.z + e.z);
  o.w = (bf16)(a.w + b.w + c.w + e.w);
  ((bf16x4*)d)[i] = o;
}

// ---------------------------------------------------------------------------
// t[b,l] = dot(lhs[b,l,:], attn_w)
// ---------------------------------------------------------------------------
__global__ __launch_bounds__(64) void tdot_kernel(const float* __restrict__ lhs,
                                                  const float* __restrict__ aw,
                                                  float* __restrict__ t) {
  const int bl = blockIdx.x;
  const int b = bl >> 5, l = bl & 31;
  const int lane = threadIdx.x;
  const float* row = lhs + ((size_t)b * SSEQ + l) * DD;
  float s = 0.f;
#pragma unroll
  for (int u = 0; u < DD / 64; ++u)
    s += row[lane + 64 * u] * aw[lane + 64 * u];
#pragma unroll
  for (int off = 32; off > 0; off >>= 1) s += __shfl_down(s, off);
  if (lane == 0) t[bl] = s;
}

// ---------------------------------------------------------------------------
// Mention pooling -> X (fp32) + Xb (bf16 shadow for MFMA GEMMs)
// ---------------------------------------------------------------------------
__global__ __launch_bounds__(256) void pool_kernel(const float* __restrict__ lhs,
                                                   const int* __restrict__ pos,
                                                   const int* __restrict__ msk,
                                                   const float* __restrict__ t,
                                                   float* __restrict__ X,
                                                   bf16* __restrict__ Xb) {
  __shared__ float wgt[LSEQ];
  __shared__ int ok[LSEQ];
  const int bm = blockIdx.x;
  const int b = bm >> 7;
  const int tid = threadIdx.x;
  if (tid < LSEQ) ok[tid] = (pos[(size_t)bm * LSEQ + tid] != -1) ? 1 : 0;
  __syncthreads();
  if (tid == 0) {
    const int mk = (msk[bm] != 0) ? 1 : 0;
    int run = 1;
    float lg[LSEQ];
    int vld[LSEQ];
#pragma unroll
    for (int l = 0; l < LSEQ; ++l) {
      run &= ok[l];
      vld[l] = mk & run;
      lg[l] = vld[l] ? t[b * LSEQ + l] : 0.f;
    }
    float mx = lg[0];
#pragma unroll
    for (int l = 1; l < LSEQ; ++l) mx = fmaxf(mx, lg[l]);
    float s = 0.f;
#pragma unroll
    for (int l = 0; l < LSEQ; ++l) { lg[l] = expf(lg[l] - mx); s += lg[l]; }
    const float inv = 1.f / s;
#pragma unroll
    for (int l = 0; l < LSEQ; ++l) wgt[l] = vld[l] ? lg[l] * inv : 0.f;
  }
  __syncthreads();
#pragma unroll
  for (int u = 0; u < 3; ++u) {
    const int d = tid + 256 * u;
    float acc = 0.f;
#pragma unroll
    for (int l = 0; l < LSEQ; ++l)
      acc += wgt[l] * lhs[((size_t)b * SSEQ + l) * DD + d];
    X[(size_t)bm * DD + d] = acc;
    Xb[(size_t)bm * DD + d] = (bf16)acc;
  }
}

// ---------------------------------------------------------------------------
// MFMA GEMM, T3 2-phase double-buffered (latency-exposed-regime fix):
// C[M,N] = A[M,K](bf16) * B[N,K](bf16)^T + bias. 128x128 tile, BK=32,
// 256 thr = 4 waves (2x2 of 64x64 wave tiles). Next K-tile's
// global_load_lds is issued BEFORE current tile's ds_read+MFMA, so the
// single __syncthreads per step (which drains vmcnt) waits ~300+ cycles
// after issue instead of 0. One barrier per K-step (was two).
// Split-K: blockIdx.z processes K window [z*K, (z+1)*K); partial written to
// Cp + z*rows*ldc. Consumers (ln_kernel / red4_bf16) sum partials.
// ---------------------------------------------------------------------------
template <int OUT_BF16, int RELU, int HAS_BIAS, int GUARD_N>
__global__ __launch_bounds__(256) void gemm_mfma(const bf16* __restrict__ A,
                                                 const bf16* __restrict__ B,
                                                 const float* __restrict__ bias,
                                                 void* __restrict__ Cp,
                                                 int K, int lda, int ldb,
                                                 int ldc, int ncols) {
  __shared__ __align__(16) bf16 As[2][128 * 32];
  __shared__ __align__(16) bf16 Bs[2][128 * 32];
  const int tid = threadIdx.x;
  const int wave = tid >> 6, lane = tid & 63;
  const int rb = blockIdx.y * 128, cb = blockIdx.x * 128;
  const int wm = (wave >> 1) * 64, wn = (wave & 1) * 64;
  const int koff = blockIdx.z * K;

  // staging: wave w covers rows [w*32, w*32+32); lane -> (row, k) so that
  // LDS element index == wave*1024 + lane*8 (row-major [128][32], no pad)
  const int sr = wave * 32 + (lane >> 2);
  const int sk = (lane & 3) * 8;
  const bf16* ga0 = A + (size_t)(rb + sr) * lda + koff + sk;
  const bf16* ga1 = A + (size_t)(rb + sr + 16) * lda + koff + sk;
  const bf16* gb0 = B + (size_t)(cb + sr) * ldb + koff + sk;
  const bf16* gb1 = B + (size_t)(cb + sr + 16) * ldb + koff + sk;
  const int so = wave * 1024;  // element offset of this wave's staging slot

  // fragment addressing: A[m=lane&15][k=(lane>>4)*8 + j]
  const int fr = lane & 15, fk = (lane >> 4) * 8;

  f32x4 acc[4][4];
#pragma unroll
  for (int i = 0; i < 4; ++i)
#pragma unroll
    for (int j = 0; j < 4; ++j) acc[i][j] = (f32x4)0.f;

  // prologue: stage K-step 0 into buffer 0
  gl2lds16(ga0, &As[0][so]); gl2lds16(ga1, &As[0][so + 512]);
  gl2lds16(gb0, &Bs[0][so]); gl2lds16(gb1, &Bs[0][so + 512]);
  ga0 += 32; ga1 += 32; gb0 += 32; gb1 += 32;
  __syncthreads();  // drains vmcnt: buffer 0 ready

  const int nsteps = K >> 5;
  int cur = 0;
  for (int t = 0; t < nsteps; ++t) {
    if (t + 1 < nsteps) {  // issue next tile's loads BEFORE compute
      const int nxt = cur ^ 1;
      gl2lds16(ga0, &As[nxt][so]); gl2lds16(ga1, &As[nxt][so + 512]);
      gl2lds16(gb0, &Bs[nxt][so]); gl2lds16(gb1, &Bs[nxt][so + 512]);
      ga0 += 32; ga1 += 32; gb0 += 32; gb1 += 32;
    }
    __builtin_amdgcn_sched_barrier(0);  // keep prefetch issue ahead of ds_read
    bf16x8 af[4], bfr[4];
#pragma unroll
    for (int i = 0; i < 4; ++i)
      af[i] = *(const bf16x8*)(&As[cur][(wm + i * 16 + fr) * 32 + fk]);
#pragma unroll
    for (int j = 0; j < 4; ++j)
      bfr[j] = *(const bf16x8*)(&Bs[cur][(wn + j * 16 + fr) * 32 + fk]);
#pragma unroll
    for (int i = 0; i < 4; ++i)
#pragma unroll
      for (int j = 0; j < 4; ++j)
        acc[i][j] = __builtin_amdgcn_mfma_f32_16x16x32_bf16(af[i], bfr[j],
                                                            acc[i][j], 0, 0, 0);
    __syncthreads();  // drains prefetch vmcnt + protects read buffer
    cur ^= 1;
  }

  // epilogue: C/D layout col=lane&15, row=(lane>>4)*4+reg (m89-verified)
  const size_t zoff = (size_t)blockIdx.z * (size_t)(gridDim.y << 7) * ldc;
  const int r0 = rb + wm + ((lane >> 4) << 2);
  const int c0 = cb + wn + fr;
#pragma unroll
  for (int i = 0; i < 4; ++i) {
#pragma unroll
    for (int j = 0; j < 4; ++j) {
      const int col = c0 + j * 16;
      if (GUARD_N && col >= ncols) continue;
      const float bv = HAS_BIAS ? bias[col] : 0.f;
#pragma unroll
      for (int r = 0; r < 4; ++r) {
        float v = acc[i][j][r] + bv;
        if (RELU) v = fmaxf(v, 0.f);
        const int row = r0 + i * 16 + r;
        if (OUT_BF16)
          ((bf16*)Cp)[zoff + (size_t)row * ldc + col] = (bf16)v;
        else
          ((float*)Cp)[zoff + (size_t)row * ldc + col] = v;
      }
    }
  }
}

// ---------------------------------------------------------------------------
// Attention: one block per (b, h). Reads fp32 QKV, writes bf16 AO.
// ---------------------------------------------------------------------------
__global__ __launch_bounds__(256) void attn_kernel(const float* __restrict__ qkv,
                                                   bf16* __restrict__ ao) {
  __shared__ float smem[2 * 64 * 132 + 128 * 132];
  float* Qs = smem;                  // [64][132] k-major
  float* Ks = smem + 64 * 132;       // [64][132]
  float* Ps = smem + 2 * 64 * 132;   // [128][132] c-major
  float* Vs = smem;                  // alias after S built: [128][68]

  const int tid = threadIdx.x;
  const int b = blockIdx.x / NHEAD;
  const int h = blockIdx.x % NHEAD;
  const float* base = qkv + (size_t)b * NMENT * (3 * DD) + h * HDIM;

#pragma unroll
  for (int it = 0; it < 8; ++it) {
    const int idx = tid + it * 256;
    const int m = idx >> 4;
    const int d0 = (idx & 15) * 4;
    const float4 q = *(const float4*)(base + (size_t)m * (3 * DD) + d0);
    const float4 k = *(const float4*)(base + (size_t)m * (3 * DD) + DD + d0);
    Qs[(d0 + 0) * 132 + m] = q.x; Qs[(d0 + 1) * 132 + m] = q.y;
    Qs[(d0 + 2) * 132 + m] = q.z; Qs[(d0 + 3) * 132 + m] = q.w;
    Ks[(d0 + 0) * 132 + m] = k.x; Ks[(d0 + 1) * 132 + m] = k.y;
    Ks[(d0 + 2) * 132 + m] = k.z; Ks[(d0 + 3) * 132 + m] = k.w;
  }
  __syncthreads();

  const int tm = (tid >> 4) * 8;
  const int tn = (tid & 15) * 8;
  {
    float acc[8][8];
#pragma unroll
    for (int i = 0; i < 8; ++i)
#pragma unroll
      for (int j = 0; j < 8; ++j) acc[i][j] = 0.f;
    for (int d = 0; d < HDIM; ++d) {
      float a[8], bv[8];
      *(float4*)&a[0] = *(const float4*)&Qs[d * 132 + tm];
      *(float4*)&a[4] = *(const float4*)&Qs[d * 132 + tm + 4];
      *(float4*)&bv[0] = *(const float4*)&Ks[d * 132 + tn];
      *(float4*)&bv[4] = *(const float4*)&Ks[d * 132 + tn + 4];
#pragma unroll
      for (int i = 0; i < 8; ++i)
#pragma unroll
        for (int j = 0; j < 8; ++j)
          acc[i][j] = fmaf(a[i], bv[j], acc[i][j]);
    }
    const float scale = 0.125f;
#pragma unroll
    for (int i = 0; i < 8; ++i)
#pragma unroll
      for (int j = 0; j < 8; ++j)
        Ps[(tn + j) * 132 + (tm + i)] = acc[i][j] * scale;
  }
  __syncthreads();

#pragma unroll
  for (int it = 0; it < 8; ++it) {
    const int idx = tid + it * 256;
    const int m = idx >> 4;
    const int d0 = (idx & 15) * 4;
    const float4 v = *(const float4*)(base + (size_t)m * (3 * DD) + 2 * DD + d0);
    *(float4*)&Vs[m * 68 + d0] = v;
  }
  if (tid < NMENT) {
    const int r = tid;
    float mx = -1e30f;
    for (int c = 0; c < NMENT; ++c) mx = fmaxf(mx, Ps[c * 132 + r]);
    float s = 0.f;
    for (int c = 0; c < NMENT; ++c) {
      const float e = expf(Ps[c * 132 + r] - mx);
      Ps[c * 132 + r] = e;
      s += e;
    }
    const float inv = 1.f / s;
    for (int c = 0; c < NMENT; ++c) Ps[c * 132 + r] *= inv;
  }
  __syncthreads();

  const int om = (tid >> 4) * 8;
  const int od = (tid & 15) * 4;
  float oacc[8][4];
#pragma unroll
  for (int i = 0; i < 8; ++i)
#pragma unroll
    for (int j = 0; j < 4; ++j) oacc[i][j] = 0.f;
  for (int c = 0; c < NMENT; ++c) {
    float p[8];
    *(float4*)&p[0] = *(const float4*)&Ps[c * 132 + om];
    *(float4*)&p[4] = *(const float4*)&Ps[c * 132 + om + 4];
    const float4 vv = *(const float4*)&Vs[c * 68 + od];
#pragma unroll
    for (int i = 0; i < 8; ++i) {
      oacc[i][0] = fmaf(p[i], vv.x, oacc[i][0]);
      oacc[i][1] = fmaf(p[i], vv.y, oacc[i][1]);
      oacc[i][2] = fmaf(p[i], vv.z, oacc[i][2]);
      oacc[i][3] = fmaf(p[i], vv.w, oacc[i][3]);
    }
  }
#pragma unroll
  for (int i = 0; i < 8; ++i) {
    bf16x4 ov;
    ov.x = (bf16)oacc[i][0]; ov.y = (bf16)oacc[i][1];
    ov.z = (bf16)oacc[i][2]; ov.w = (bf16)oacc[i][3];
    *(bf16x4*)(ao + (size_t)(b * NMENT + om + i) * DD + h * HDIM + od) = ov;
  }
}

// ---------------------------------------------------------------------------
// out = LayerNorm(x + bias + sum_{n<NS} y_n) * w + b -> fp32 o + bf16 ob
// y_n are split-K GEMM partials at stride NM*DD; bias is the GEMM bias
// folded here (split partials carry no bias).
// ---------------------------------------------------------------------------
template <int NS>
__global__ __launch_bounds__(256) void ln_kernel(const float* __restrict__ x,
                                                 const float* __restrict__ y,
                                                 const float* __restrict__ bias,
                                                 const float* __restrict__ w,
                                                 const float* __restrict__ bb,
                                                 float* __restrict__ o,
                                                 bf16* __restrict__ ob) {
  __shared__ float red1[4], red2[4];
  __shared__ float mshare, vshare;
  const int row = blockIdx.x;
  const int tid = threadIdx.x;
  const int wave = tid >> 6, lane = tid & 63;
  const float* xr = x + (size_t)row * DD;
  const float* yr = y + (size_t)row * DD;
  float v[3];
  float s = 0.f;
#pragma unroll
  for (int u = 0; u < 3; ++u) {
    const int d = tid + 256 * u;
    float acc = xr[d] + bias[d];
#pragma unroll
    for (int n = 0; n < NS; ++n) acc += yr[(size_t)n * NM * DD + d];
    v[u] = acc;
    s += acc;
  }
#pragma unroll
  for (int off = 32; off > 0; off >>= 1) s += __shfl_down(s, off);
  if (lane == 0) red1[wave] = s;
  __syncthreads();
  if (tid == 0) mshare = (red1[0] + red1[1] + red1[2] + red1[3]) * (1.f / DD);
  __syncthreads();
  const float mean = mshare;
  float q = 0.f;
#pragma unroll
  for (int u = 0; u < 3; ++u) { const float d = v[u] - mean; q += d * d; }
#pragma unroll
  for (int off = 32; off > 0; off >>= 1) q += __shfl_down(q, off);
  if (lane == 0) red2[wave] = q;
  __syncthreads();
  if (tid == 0)
    vshare = rsqrtf((red2[0] + red2[1] + red2[2] + red2[3]) * (1.f / DD) + 1e-5f);
  __syncthreads();
  const float rstd = vshare;
  float* orow = o + (size_t)row * DD;
  bf16* brow = ob + (size_t)row * DD;
#pragma unroll
  for (int u = 0; u < 3; ++u) {
    const int d = tid + 256 * u;
    const float r = (v[u] - mean) * rstd * w[d] + bb[d];
    orow[d] = r;
    brow[d] = (bf16)r;
  }
}

// ---------------------------------------------------------------------------
extern "C" void kernel_launch(void* const* d_in, const int* in_sizes, int n_in,
                              void* d_out, int out_size, void* d_ws, size_t ws_size,
                              hipStream_t stream) {
  const float* lhs    = (const float*)d_in[0];
  const int*   pos    = (const int*)d_in[1];
  const int*   msk    = (const int*)d_in[2];
  const float* attn_w = (const float*)d_in[3];
  // d_in[4] attn_b cancels in softmax
  const float* qkv_w  = (const float*)d_in[5];
  const float* qkv_b  = (const float*)d_in[6];
  const float* out_w  = (const float*)d_in[7];
  const float* out_b  = (const float*)d_in[8];
  const float* ff1_w  = (const float*)d_in[11];
  const float* ff1_b  = (const float*)d_in[12];
  const float* ff2_w  = (const float*)d_in[13];
  const float* ff2_b  = (const float*)d_in[14];
  const float* ln1_w  = (const float*)d_in[9];
  const float* ln1_b  = (const float*)d_in[10];
  const float* ln2_w  = (const float*)d_in[15];
  const float* ln2_b  = (const float*)d_in[16];
  const float* cls_w1 = (const float*)d_in[17];
  const float* cls_w2 = (const float*)d_in[18];
  const float* cls_b2 = (const float*)d_in[19];
  float* out = (float*)d_out;

  // workspace carve-up (~121 MB total).
  // SCR is a union region (25.2 MB = 4*NM*DD fp32):
  //   - holds QKV fp32 [NM][2304] between the QKV GEMM and attn
  //   - then holds split-K partials (<=4 x [NM][DD] fp32) for out-proj/FF2
  //   - holds 4 x [NM][128] partials for the Hb classifier stage
  char* p = (char*)d_ws;
  auto carve = [&](size_t bytes) {
    void* r = (void*)p;
    p += (bytes + 255) & ~(size_t)255;
    return r;
  };
  float* T    = (float*)carve(512 * 4);
  float* X    = (float*)carve((size_t)NM * DD * 4);
  float* SCR  = (float*)carve((size_t)4 * NM * DD * 4);
  bf16* Xb    = (bf16*)carve((size_t)NM * DD * 2);
  bf16* AOb   = (bf16*)carve((size_t)NM * DD * 2);
  bf16* H1    = (bf16*)carve((size_t)NM * DFF * 2);
  bf16* Hb    = (bf16*)carve((size_t)NM * 128 * 2);
  bf16* Wqkv  = (bf16*)carve((size_t)NLAYER * 3 * DD * DD * 2);
  bf16* Wout  = (bf16*)carve((size_t)NLAYER * DD * DD * 2);
  bf16* Wff1  = (bf16*)carve((size_t)NLAYER * DFF * DD * 2);
  bf16* Wff2  = (bf16*)carve((size_t)NLAYER * DD * DFF * 2);
  bf16* Wc1   = (bf16*)carve((size_t)128 * DD * 2);
  bf16* Wc2   = (bf16*)carve((size_t)50048 * 128 * 2);

  // fused weight conversions (one dispatch, ~210 MB traffic ~ 35 us)
  conv_all<<<(C_TOTAL + 255) / 256, 256, 0, stream>>>(
      qkv_w, out_w, ff1_w, ff2_w, cls_w1, cls_w2,
      Wqkv, Wout, Wff1, Wff2, Wc1, Wc2);

  tdot_kernel<<<NBATCH * LSEQ, 64, 0, stream>>>(lhs, attn_w, T);
  pool_kernel<<<NM, 256, 0, stream>>>(lhs, pos, msk, T, X, Xb);

  for (int i = 0; i < NLAYER; ++i) {
    // QKV projection: [2048][768] x [2304][768]^T -> SCR fp32 [2048][2304]
    gemm_mfma<0, 0, 1, 0><<<dim3(18, 16), 256, 0, stream>>>(
        Xb, Wqkv + (size_t)i * 3 * DD * DD, qkv_b + (size_t)i * 3 * DD, SCR,
        DD, DD, DD, 3 * DD, 3 * DD);
    attn_kernel<<<NBATCH * NHEAD, 256, 0, stream>>>(SCR, AOb);
    // out-proj split-K x2 (96 -> 192 blocks): partials, bias folded into ln1
    gemm_mfma<0, 0, 0, 0><<<dim3(6, 16, 2), 256, 0, stream>>>(
        AOb, Wout + (size_t)i * DD * DD, nullptr, SCR,
        DD / 2, DD, DD, DD, DD);
    ln_kernel<2><<<NM, 256, 0, stream>>>(X, SCR, out_b + (size_t)i * DD,
                                         ln1_w + (size_t)i * DD,
                                         ln1_b + (size_t)i * DD, X, Xb);
    // FF1: full-K (384 blocks already fill the chip)
    gemm_mfma<1, 1, 1, 0><<<dim3(24, 16), 256, 0, stream>>>(
        Xb, Wff1 + (size_t)i * DFF * DD, ff1_b + (size_t)i * DFF, H1,
        DD, DD, DD, DFF, DFF);
    // FF2 split-K x4 (96 -> 384 blocks, K 3072 -> 768/split)
    gemm_mfma<0, 0, 0, 0><<<dim3(6, 16, 4), 256, 0, stream>>>(
        H1, Wff2 + (size_t)i * DD * DFF, nullptr, SCR,
        DFF / 4, DFF, DFF, DD, DD);
    ln_kernel<4><<<NM, 256, 0, stream>>>(X, SCR, ff2_b + (size_t)i * DD,
                                         ln2_w + (size_t)i * DD,
                                         ln2_b + (size_t)i * DD, X, Xb);
  }

  // classifier stage 1: Xb @ Wc1^T, split-K x4 (16 -> 64 blocks) -> fp32
  // partials in SCR, then reduce+convert -> Hb [2048][128] bf16
  gemm_mfma<0, 0, 0, 0><<<dim3(1, 16, 4), 256, 0, stream>>>(
      Xb, Wc1, nullptr, SCR, DD / 4, DD, DD, 128, 128);
  {
    const int n4 = NM * 128 / 4;  // 65,536 float4 chunks per partial
    red4_bf16<<<(n4 + 255) / 256, 256, 0, stream>>>(SCR, Hb, n4);
  }
  // classifier stage 2: Hb @ Wc2^T + b -> out [2048][50000] fp32
  gemm_mfma<0, 0, 1, 1><<<dim3(391, 16), 256, 0, stream>>>(
      Hb, Wc2, cls_b2, out, 128, 128, 128, NENT, NENT);
}

// Round 3
// 1094.589 us; speedup vs baseline: 1.0636x; 1.0237x over previous
//
#include <hip/hip_runtime.h>
#include <math.h>

// Problem constants
#define NBATCH 16
#define NMENT  128          // M
#define NM     2048         // B*M rows
#define LSEQ   32
#define SSEQ   512
#define DD     768
#define NHEAD  12
#define HDIM   64
#define DFF    3072
#define NLAYER 4
#define NENT   50000

typedef __bf16 bf16;
typedef __attribute__((__ext_vector_type__(4))) float f32x4;
typedef __attribute__((__ext_vector_type__(8))) bf16 bf16x8;
typedef __attribute__((__ext_vector_type__(4))) bf16 bf16x4;

// ---------------------------------------------------------------------------
// async global->LDS, 16B per lane (dest = wave-uniform base + lane*16)
// ---------------------------------------------------------------------------
__device__ __forceinline__ void gl2lds16(const bf16* g, bf16* l) {
  __builtin_amdgcn_global_load_lds(
      (const __attribute__((address_space(1))) void*)g,
      (__attribute__((address_space(3))) void*)l, 16, 0, 0);
}

// ---------------------------------------------------------------------------
// Fused weight conversion: all fp32->bf16 weight converts in ONE dispatch.
// ---------------------------------------------------------------------------
#define C_QKV (NLAYER * 3 * DD * DD / 4)   // 1,769,472 float4 chunks
#define C_OUT (NLAYER * DD * DD / 4)       //   589,824
#define C_FF  (NLAYER * DFF * DD / 4)      // 2,359,296
#define C_W1  (128 * DD)                   //    98,304 elements
#define C_W2  (50048 * 128)                // 6,406,144 elements
#define C_TOTAL (C_QKV + C_OUT + 2 * C_FF + C_W1 + C_W2)

__device__ __forceinline__ void cvt4(const float* s, bf16* d, int i) {
  const float4 v = ((const float4*)s)[i];
  bf16x4 o;
  o.x = (bf16)v.x; o.y = (bf16)v.y; o.z = (bf16)v.z; o.w = (bf16)v.w;
  ((bf16x4*)d)[i] = o;
}

__global__ __launch_bounds__(256) void conv_all(
    const float* __restrict__ qkv_w, const float* __restrict__ out_w,
    const float* __restrict__ ff1_w, const float* __restrict__ ff2_w,
    const float* __restrict__ cls_w1, const float* __restrict__ cls_w2,
    bf16* __restrict__ Wqkv, bf16* __restrict__ Wout, bf16* __restrict__ Wff1,
    bf16* __restrict__ Wff2, bf16* __restrict__ Wc1, bf16* __restrict__ Wc2) {
  int i = blockIdx.x * 256 + threadIdx.x;
  if (i < C_QKV) { cvt4(qkv_w, Wqkv, i); return; }
  i -= C_QKV;
  if (i < C_OUT) { cvt4(out_w, Wout, i); return; }
  i -= C_OUT;
  if (i < C_FF) { cvt4(ff1_w, Wff1, i); return; }
  i -= C_FF;
  if (i < C_FF) { cvt4(ff2_w, Wff2, i); return; }
  i -= C_FF;
  if (i < C_W1) {  // [100][768] -> [128][768] zero-padded
    const int r = i / DD;
    Wc1[i] = (bf16)((r < 100) ? cls_w1[i] : 0.f);
    return;
  }
  i -= C_W1;
  if (i < C_W2) {  // [50000][100] -> [50048][128] zero-padded
    const int r = i >> 7, c = i & 127;
    const float v = (r < NENT && c < 100) ? cls_w2[r * 100 + c] : 0.f;
    Wc2[i] = (bf16)v;
  }
}

// sum 4 fp32 partials (stride n4 float4s) -> bf16
__global__ __launch_bounds__(256) void red4_bf16(const float* __restrict__ p,
                                                 bf16* __restrict__ d, int n4) {
  const int i = blockIdx.x * 256 + threadIdx.x;
  if (i >= n4) return;
  const float4 a = ((const float4*)p)[i];
  const float4 b = ((const float4*)p)[i + (size_t)n4];
  const float4 c = ((const float4*)p)[i + 2 * (size_t)n4];
  const float4 e = ((const float4*)p)[i + 3 * (size_t)n4];
  bf16x4 o;
  o.x = (bf16)(a.x + b.x + c.x + e.x);
  o.y = (bf16)(a.y + b.y + c.y + e.y);
  o.z = (bf16)(a.z + b.z + c.z + e.z);
  o.w = (bf16)(a.w + b.w + c.w + e.w);
  ((bf16x4*)d)[i] = o;
}

// ---------------------------------------------------------------------------
// t[b,l] = dot(lhs[b,l,:], attn_w)
// ---------------------------------------------------------------------------
__global__ __launch_bounds__(64) void tdot_kernel(const float* __restrict__ lhs,
                                                  const float* __restrict__ aw,
                                                  float* __restrict__ t) {
  const int bl = blockIdx.x;
  const int b = bl >> 5, l = bl & 31;
  const int lane = threadIdx.x;
  const float* row = lhs + ((size_t)b * SSEQ + l) * DD;
  float s = 0.f;
#pragma unroll
  for (int u = 0; u < DD / 64; ++u)
    s += row[lane + 64 * u] * aw[lane + 64 * u];
#pragma unroll
  for (int off = 32; off > 0; off >>= 1) s += __shfl_down(s, off);
  if (lane == 0) t[bl] = s;
}

// ---------------------------------------------------------------------------
// Mention pooling -> X (fp32) + Xb (bf16 shadow for MFMA GEMMs)
// ---------------------------------------------------------------------------
__global__ __launch_bounds__(256) void pool_kernel(const float* __restrict__ lhs,
                                                   const int* __restrict__ pos,
                                                   const int* __restrict__ msk,
                                                   const float* __restrict__ t,
                                                   float* __restrict__ X,
                                                   bf16* __restrict__ Xb) {
  __shared__ float wgt[LSEQ];
  __shared__ int ok[LSEQ];
  const int bm = blockIdx.x;
  const int b = bm >> 7;
  const int tid = threadIdx.x;
  if (tid < LSEQ) ok[tid] = (pos[(size_t)bm * LSEQ + tid] != -1) ? 1 : 0;
  __syncthreads();
  if (tid == 0) {
    const int mk = (msk[bm] != 0) ? 1 : 0;
    int run = 1;
    float lg[LSEQ];
    int vld[LSEQ];
#pragma unroll
    for (int l = 0; l < LSEQ; ++l) {
      run &= ok[l];
      vld[l] = mk & run;
      lg[l] = vld[l] ? t[b * LSEQ + l] : 0.f;
    }
    float mx = lg[0];
#pragma unroll
    for (int l = 1; l < LSEQ; ++l) mx = fmaxf(mx, lg[l]);
    float s = 0.f;
#pragma unroll
    for (int l = 0; l < LSEQ; ++l) { lg[l] = expf(lg[l] - mx); s += lg[l]; }
    const float inv = 1.f / s;
#pragma unroll
    for (int l = 0; l < LSEQ; ++l) wgt[l] = vld[l] ? lg[l] * inv : 0.f;
  }
  __syncthreads();
#pragma unroll
  for (int u = 0; u < 3; ++u) {
    const int d = tid + 256 * u;
    float acc = 0.f;
#pragma unroll
    for (int l = 0; l < LSEQ; ++l)
      acc += wgt[l] * lhs[((size_t)b * SSEQ + l) * DD + d];
    X[(size_t)bm * DD + d] = acc;
    Xb[(size_t)bm * DD + d] = (bf16)acc;
  }
}

// ---------------------------------------------------------------------------
// MFMA GEMM, 3-buffer counted-vmcnt pipeline (T3+T4 on 128x128 tile):
// C[M,N] = A[M,K](bf16) * B[N,K](bf16)^T + bias. BK=32, 256 thr = 4 waves.
// Prologue stages 3 K-tiles; each iteration waits vmcnt(8) (2 tiles still
// in flight), raw s_barrier, ds_read+MFMA, s_barrier, then re-stages the
// just-consumed buffer for tile t+3. Issue-to-wait distance = 2 compute
// phases (~500+ cyc) -> covers L2/L3 latency. No vmcnt(0) drain in the
// main loop (peeled tail uses vmcnt(4)/vmcnt(0)).
// vmcnt math: at iter t a wave's own outstanding loads = 4*min(2, nsteps-1-t).
// LDS 48 KB -> 2-3 blocks/CU co-residency (kills grid tails).
// Split-K: blockIdx.z processes K window [z*K, (z+1)*K); partial written to
// Cp + z*rows*ldc. Consumers (ln_kernel / red4_bf16) sum partials.
// ---------------------------------------------------------------------------
template <int OUT_BF16, int RELU, int HAS_BIAS, int GUARD_N>
__global__ __launch_bounds__(256) void gemm_mfma(const bf16* __restrict__ A,
                                                 const bf16* __restrict__ B,
                                                 const float* __restrict__ bias,
                                                 void* __restrict__ Cp,
                                                 int K, int lda, int ldb,
                                                 int ldc, int ncols) {
  __shared__ __align__(16) bf16 As[3][128 * 32];
  __shared__ __align__(16) bf16 Bs[3][128 * 32];
  const int tid = threadIdx.x;
  const int wave = tid >> 6, lane = tid & 63;
  const int rb = blockIdx.y * 128, cb = blockIdx.x * 128;
  const int wm = (wave >> 1) * 64, wn = (wave & 1) * 64;
  const int koff = blockIdx.z * K;

  // staging: wave w covers rows [w*32, w*32+32); lane -> (row, k) so that
  // LDS element index == wave*1024 + lane*8 (row-major [128][32], no pad)
  const int sr = wave * 32 + (lane >> 2);
  const int sk = (lane & 3) * 8;
  const bf16* ga0 = A + (size_t)(rb + sr) * lda + koff + sk;
  const bf16* ga1 = A + (size_t)(rb + sr + 16) * lda + koff + sk;
  const bf16* gb0 = B + (size_t)(cb + sr) * ldb + koff + sk;
  const bf16* gb1 = B + (size_t)(cb + sr + 16) * ldb + koff + sk;
  const int so = wave * 1024;  // element offset of this wave's staging slot

  // fragment addressing: A[m=lane&15][k=(lane>>4)*8 + j]
  const int fr = lane & 15, fk = (lane >> 4) * 8;

  const int nsteps = K >> 5;

  // stage tile into buffer b, advancing global pointers (sequential tiles)
  auto stage = [&](int bsel) {
    bf16* sa = &As[bsel][so];
    bf16* sb = &Bs[bsel][so];
    gl2lds16(ga0, sa); gl2lds16(ga1, sa + 512);
    gl2lds16(gb0, sb); gl2lds16(gb1, sb + 512);
    ga0 += 32; ga1 += 32; gb0 += 32; gb1 += 32;
  };

  f32x4 acc[4][4];
#pragma unroll
  for (int i = 0; i < 4; ++i)
#pragma unroll
    for (int j = 0; j < 4; ++j) acc[i][j] = (f32x4)0.f;

  // prologue: fill up to 3 buffers (no barrier needed yet)
  stage(0);
  if (nsteps > 1) stage(1);
  if (nsteps > 2) stage(2);

  int cur = 0;
  for (int t = 0; t < nsteps; ++t) {
    // wait for tile t's loads (own-wave count; barrier makes it global)
    if (t < nsteps - 2)
      asm volatile("s_waitcnt vmcnt(8)" ::: "memory");
    else if (t == nsteps - 2)
      asm volatile("s_waitcnt vmcnt(4)" ::: "memory");
    else
      asm volatile("s_waitcnt vmcnt(0)" ::: "memory");
    __builtin_amdgcn_s_barrier();   // all waves' tile-t loads now visible

    bf16x8 af[4], bfr[4];
#pragma unroll
    for (int i = 0; i < 4; ++i)
      af[i] = *(const bf16x8*)(&As[cur][(wm + i * 16 + fr) * 32 + fk]);
#pragma unroll
    for (int j = 0; j < 4; ++j)
      bfr[j] = *(const bf16x8*)(&Bs[cur][(wn + j * 16 + fr) * 32 + fk]);
#pragma unroll
    for (int i = 0; i < 4; ++i)
#pragma unroll
      for (int j = 0; j < 4; ++j)
        acc[i][j] = __builtin_amdgcn_mfma_f32_16x16x32_bf16(af[i], bfr[j],
                                                            acc[i][j], 0, 0, 0);

    __builtin_amdgcn_s_barrier();   // all waves done reading buf[cur]
    if (t + 3 < nsteps) stage(cur); // refill just-consumed buffer (tile t+3)
    cur = (cur == 2) ? 0 : cur + 1;
  }

  // epilogue: C/D layout col=lane&15, row=(lane>>4)*4+reg (m89-verified)
  const size_t zoff = (size_t)blockIdx.z * (size_t)(gridDim.y << 7) * ldc;
  const int r0 = rb + wm + ((lane >> 4) << 2);
  const int c0 = cb + wn + fr;
#pragma unroll
  for (int i = 0; i < 4; ++i) {
#pragma unroll
    for (int j = 0; j < 4; ++j) {
      const int col = c0 + j * 16;
      if (GUARD_N && col >= ncols) continue;
      const float bv = HAS_BIAS ? bias[col] : 0.f;
#pragma unroll
      for (int r = 0; r < 4; ++r) {
        float v = acc[i][j][r] + bv;
        if (RELU) v = fmaxf(v, 0.f);
        const int row = r0 + i * 16 + r;
        if (OUT_BF16)
          ((bf16*)Cp)[zoff + (size_t)row * ldc + col] = (bf16)v;
        else
          ((float*)Cp)[zoff + (size_t)row * ldc + col] = v;
      }
    }
  }
}

// ---------------------------------------------------------------------------
// Attention: one block per (b, h). Reads fp32 QKV, writes bf16 AO.
// ---------------------------------------------------------------------------
__global__ __launch_bounds__(256) void attn_kernel(const float* __restrict__ qkv,
                                                   bf16* __restrict__ ao) {
  __shared__ float smem[2 * 64 * 132 + 128 * 132];
  float* Qs = smem;                  // [64][132] k-major
  float* Ks = smem + 64 * 132;       // [64][132]
  float* Ps = smem + 2 * 64 * 132;   // [128][132] c-major
  float* Vs = smem;                  // alias after S built: [128][68]

  const int tid = threadIdx.x;
  const int b = blockIdx.x / NHEAD;
  const int h = blockIdx.x % NHEAD;
  const float* base = qkv + (size_t)b * NMENT * (3 * DD) + h * HDIM;

#pragma unroll
  for (int it = 0; it < 8; ++it) {
    const int idx = tid + it * 256;
    const int m = idx >> 4;
    const int d0 = (idx & 15) * 4;
    const float4 q = *(const float4*)(base + (size_t)m * (3 * DD) + d0);
    const float4 k = *(const float4*)(base + (size_t)m * (3 * DD) + DD + d0);
    Qs[(d0 + 0) * 132 + m] = q.x; Qs[(d0 + 1) * 132 + m] = q.y;
    Qs[(d0 + 2) * 132 + m] = q.z; Qs[(d0 + 3) * 132 + m] = q.w;
    Ks[(d0 + 0) * 132 + m] = k.x; Ks[(d0 + 1) * 132 + m] = k.y;
    Ks[(d0 + 2) * 132 + m] = k.z; Ks[(d0 + 3) * 132 + m] = k.w;
  }
  __syncthreads();

  const int tm = (tid >> 4) * 8;
  const int tn = (tid & 15) * 8;
  {
    float acc[8][8];
#pragma unroll
    for (int i = 0; i < 8; ++i)
#pragma unroll
      for (int j = 0; j < 8; ++j) acc[i][j] = 0.f;
    for (int d = 0; d < HDIM; ++d) {
      float a[8], bv[8];
      *(float4*)&a[0] = *(const float4*)&Qs[d * 132 + tm];
      *(float4*)&a[4] = *(const float4*)&Qs[d * 132 + tm + 4];
      *(float4*)&bv[0] = *(const float4*)&Ks[d * 132 + tn];
      *(float4*)&bv[4] = *(const float4*)&Ks[d * 132 + tn + 4];
#pragma unroll
      for (int i = 0; i < 8; ++i)
#pragma unroll
        for (int j = 0; j < 8; ++j)
          acc[i][j] = fmaf(a[i], bv[j], acc[i][j]);
    }
    const float scale = 0.125f;
#pragma unroll
    for (int i = 0; i < 8; ++i)
#pragma unroll
      for (int j = 0; j < 8; ++j)
        Ps[(tn + j) * 132 + (tm + i)] = acc[i][j] * scale;
  }
  __syncthreads();

#pragma unroll
  for (int it = 0; it < 8; ++it) {
    const int idx = tid + it * 256;
    const int m = idx >> 4;
    const int d0 = (idx & 15) * 4;
    const float4 v = *(const float4*)(base + (size_t)m * (3 * DD) + 2 * DD + d0);
    *(float4*)&Vs[m * 68 + d0] = v;
  }
  if (tid < NMENT) {
    const int r = tid;
    float mx = -1e30f;
    for (int c = 0; c < NMENT; ++c) mx = fmaxf(mx, Ps[c * 132 + r]);
    float s = 0.f;
    for (int c = 0; c < NMENT; ++c) {
      const float e = expf(Ps[c * 132 + r] - mx);
      Ps[c * 132 + r] = e;
      s += e;
    }
    const float inv = 1.f / s;
    for (int c = 0; c < NMENT; ++c) Ps[c * 132 + r] *= inv;
  }
  __syncthreads();

  const int om = (tid >> 4) * 8;
  const int od = (tid & 15) * 4;
  float oacc[8][4];
#pragma unroll
  for (int i = 0; i < 8; ++i)
#pragma unroll
    for (int j = 0; j < 4; ++j) oacc[i][j] = 0.f;
  for (int c = 0; c < NMENT; ++c) {
    float p[8];
    *(float4*)&p[0] = *(const float4*)&Ps[c * 132 + om];
    *(float4*)&p[4] = *(const float4*)&Ps[c * 132 + om + 4];
    const float4 vv = *(const float4*)&Vs[c * 68 + od];
#pragma unroll
    for (int i = 0; i < 8; ++i) {
      oacc[i][0] = fmaf(p[i], vv.x, oacc[i][0]);
      oacc[i][1] = fmaf(p[i], vv.y, oacc[i][1]);
      oacc[i][2] = fmaf(p[i], vv.z, oacc[i][2]);
      oacc[i][3] = fmaf(p[i], vv.w, oacc[i][3]);
    }
  }
#pragma unroll
  for (int i = 0; i < 8; ++i) {
    bf16x4 ov;
    ov.x = (bf16)oacc[i][0]; ov.y = (bf16)oacc[i][1];
    ov.z = (bf16)oacc[i][2]; ov.w = (bf16)oacc[i][3];
    *(bf16x4*)(ao + (size_t)(b * NMENT + om + i) * DD + h * HDIM + od) = ov;
  }
}

// ---------------------------------------------------------------------------
// out = LayerNorm(x + bias + sum_{n<NS} y_n) * w + b -> fp32 o + bf16 ob
// ---------------------------------------------------------------------------
template <int NS>
__global__ __launch_bounds__(256) void ln_kernel(const float* __restrict__ x,
                                                 const float* __restrict__ y,
                                                 const float* __restrict__ bias,
                                                 const float* __restrict__ w,
                                                 const float* __restrict__ bb,
                                                 float* __restrict__ o,
                                                 bf16* __restrict__ ob) {
  __shared__ float red1[4], red2[4];
  __shared__ float mshare, vshare;
  const int row = blockIdx.x;
  const int tid = threadIdx.x;
  const int wave = tid >> 6, lane = tid & 63;
  const float* xr = x + (size_t)row * DD;
  const float* yr = y + (size_t)row * DD;
  float v[3];
  float s = 0.f;
#pragma unroll
  for (int u = 0; u < 3; ++u) {
    const int d = tid + 256 * u;
    float acc = xr[d] + bias[d];
#pragma unroll
    for (int n = 0; n < NS; ++n) acc += yr[(size_t)n * NM * DD + d];
    v[u] = acc;
    s += acc;
  }
#pragma unroll
  for (int off = 32; off > 0; off >>= 1) s += __shfl_down(s, off);
  if (lane == 0) red1[wave] = s;
  __syncthreads();
  if (tid == 0) mshare = (red1[0] + red1[1] + red1[2] + red1[3]) * (1.f / DD);
  __syncthreads();
  const float mean = mshare;
  float q = 0.f;
#pragma unroll
  for (int u = 0; u < 3; ++u) { const float d = v[u] - mean; q += d * d; }
#pragma unroll
  for (int off = 32; off > 0; off >>= 1) q += __shfl_down(q, off);
  if (lane == 0) red2[wave] = q;
  __syncthreads();
  if (tid == 0)
    vshare = rsqrtf((red2[0] + red2[1] + red2[2] + red2[3]) * (1.f / DD) + 1e-5f);
  __syncthreads();
  const float rstd = vshare;
  float* orow = o + (size_t)row * DD;
  bf16* brow = ob + (size_t)row * DD;
#pragma unroll
  for (int u = 0; u < 3; ++u) {
    const int d = tid + 256 * u;
    const float r = (v[u] - mean) * rstd * w[d] + bb[d];
    orow[d] = r;
    brow[d] = (bf16)r;
  }
}

// ---------------------------------------------------------------------------
extern "C" void kernel_launch(void* const* d_in, const int* in_sizes, int n_in,
                              void* d_out, int out_size, void* d_ws, size_t ws_size,
                              hipStream_t stream) {
  const float* lhs    = (const float*)d_in[0];
  const int*   pos    = (const int*)d_in[1];
  const int*   msk    = (const int*)d_in[2];
  const float* attn_w = (const float*)d_in[3];
  // d_in[4] attn_b cancels in softmax
  const float* qkv_w  = (const float*)d_in[5];
  const float* qkv_b  = (const float*)d_in[6];
  const float* out_w  = (const float*)d_in[7];
  const float* out_b  = (const float*)d_in[8];
  const float* ff1_w  = (const float*)d_in[11];
  const float* ff1_b  = (const float*)d_in[12];
  const float* ff2_w  = (const float*)d_in[13];
  const float* ff2_b  = (const float*)d_in[14];
  const float* ln1_w  = (const float*)d_in[9];
  const float* ln1_b  = (const float*)d_in[10];
  const float* ln2_w  = (const float*)d_in[15];
  const float* ln2_b  = (const float*)d_in[16];
  const float* cls_w1 = (const float*)d_in[17];
  const float* cls_w2 = (const float*)d_in[18];
  const float* cls_b2 = (const float*)d_in[19];
  float* out = (float*)d_out;

  // workspace carve-up (~121 MB total).
  // SCR is a union region (25.2 MB = 4*NM*DD fp32):
  //   - holds QKV fp32 [NM][2304] between the QKV GEMM and attn
  //   - then holds split-K partials (<=4 x [NM][DD] fp32) for out-proj/FF2
  //   - holds 4 x [NM][128] partials for the Hb classifier stage
  char* p = (char*)d_ws;
  auto carve = [&](size_t bytes) {
    void* r = (void*)p;
    p += (bytes + 255) & ~(size_t)255;
    return r;
  };
  float* T    = (float*)carve(512 * 4);
  float* X    = (float*)carve((size_t)NM * DD * 4);
  float* SCR  = (float*)carve((size_t)4 * NM * DD * 4);
  bf16* Xb    = (bf16*)carve((size_t)NM * DD * 2);
  bf16* AOb   = (bf16*)carve((size_t)NM * DD * 2);
  bf16* H1    = (bf16*)carve((size_t)NM * DFF * 2);
  bf16* Hb    = (bf16*)carve((size_t)NM * 128 * 2);
  bf16* Wqkv  = (bf16*)carve((size_t)NLAYER * 3 * DD * DD * 2);
  bf16* Wout  = (bf16*)carve((size_t)NLAYER * DD * DD * 2);
  bf16* Wff1  = (bf16*)carve((size_t)NLAYER * DFF * DD * 2);
  bf16* Wff2  = (bf16*)carve((size_t)NLAYER * DD * DFF * 2);
  bf16* Wc1   = (bf16*)carve((size_t)128 * DD * 2);
  bf16* Wc2   = (bf16*)carve((size_t)50048 * 128 * 2);

  // fused weight conversions (one dispatch, ~315 MB traffic ~ 50 us)
  conv_all<<<(C_TOTAL + 255) / 256, 256, 0, stream>>>(
      qkv_w, out_w, ff1_w, ff2_w, cls_w1, cls_w2,
      Wqkv, Wout, Wff1, Wff2, Wc1, Wc2);

  tdot_kernel<<<NBATCH * LSEQ, 64, 0, stream>>>(lhs, attn_w, T);
  pool_kernel<<<NM, 256, 0, stream>>>(lhs, pos, msk, T, X, Xb);

  for (int i = 0; i < NLAYER; ++i) {
    // QKV projection: [2048][768] x [2304][768]^T -> SCR fp32 [2048][2304]
    gemm_mfma<0, 0, 1, 0><<<dim3(18, 16), 256, 0, stream>>>(
        Xb, Wqkv + (size_t)i * 3 * DD * DD, qkv_b + (size_t)i * 3 * DD, SCR,
        DD, DD, DD, 3 * DD, 3 * DD);
    attn_kernel<<<NBATCH * NHEAD, 256, 0, stream>>>(SCR, AOb);
    // out-proj split-K x2 (192 blocks): partials, bias folded into ln1
    gemm_mfma<0, 0, 0, 0><<<dim3(6, 16, 2), 256, 0, stream>>>(
        AOb, Wout + (size_t)i * DD * DD, nullptr, SCR,
        DD / 2, DD, DD, DD, DD);
    ln_kernel<2><<<NM, 256, 0, stream>>>(X, SCR, out_b + (size_t)i * DD,
                                         ln1_w + (size_t)i * DD,
                                         ln1_b + (size_t)i * DD, X, Xb);
    // FF1: full-K (384 blocks; 2-3 blocks/CU co-residency removes tail)
    gemm_mfma<1, 1, 1, 0><<<dim3(24, 16), 256, 0, stream>>>(
        Xb, Wff1 + (size_t)i * DFF * DD, ff1_b + (size_t)i * DFF, H1,
        DD, DD, DD, DFF, DFF);
    // FF2 split-K x4 (384 blocks, K 3072 -> 768/split)
    gemm_mfma<0, 0, 0, 0><<<dim3(6, 16, 4), 256, 0, stream>>>(
        H1, Wff2 + (size_t)i * DD * DFF, nullptr, SCR,
        DFF / 4, DFF, DFF, DD, DD);
    ln_kernel<4><<<NM, 256, 0, stream>>>(X, SCR, ff2_b + (size_t)i * DD,
                                         ln2_w + (size_t)i * DD,
                                         ln2_b + (size_t)i * DD, X, Xb);
  }

  // classifier stage 1: Xb @ Wc1^T, split-K x4 (64 blocks) -> fp32
  // partials in SCR, then reduce+convert -> Hb [2048][128] bf16
  gemm_mfma<0, 0, 0, 0><<<dim3(1, 16, 4), 256, 0, stream>>>(
      Xb, Wc1, nullptr, SCR, DD / 4, DD, DD, 128, 128);
  {
    const int n4 = NM * 128 / 4;  // 65,536 float4 chunks per partial
    red4_bf16<<<(n4 + 255) / 256, 256, 0, stream>>>(SCR, Hb, n4);
  }
  // classifier stage 2: Hb @ Wc2^T + b -> out [2048][50000] fp32
  gemm_mfma<0, 0, 1, 1><<<dim3(391, 16), 256, 0, stream>>>(
      Hb, Wc2, cls_b2, out, 128, 128, 128, NENT, NENT);
}